// Round 1
// baseline (270.056 us; speedup 1.0000x reference)
//
#include <hip/hip_runtime.h>

// Problem sizes (fixed by the reference)
constexpr int kB    = 2048;  // batch
constexpr int kVIS  = 2048;  // visible units (GEMM K)
constexpr int kHID  = 1024;  // hidden units (GEMM N)
constexpr int kCLS  = 64;    // classes

// ---------------- Kernel 1: pre = v @ W + c  (fp32 vector GEMM) ----------------
// 64x64 block tile, 256 threads, 4x4 micro-tile per thread, BK=16 LDS staging.
// grid = (kHID/64, kB/64) = (16, 32) = 512 blocks -> 2 blocks/CU.
constexpr int BM = 64, BN = 64, BK = 16;

__global__ __launch_bounds__(256) void gemm_vw(const float* __restrict__ V,
                                               const float* __restrict__ Wm,
                                               const float* __restrict__ cvec,
                                               float* __restrict__ pre) {
    __shared__ float As[BK][BM + 4];  // [k][m], +4 pad to break write conflicts
    __shared__ float Bs[BK][BN + 4];  // [k][n]
    const int tid = threadIdx.x;
    const int tx = tid & 15;   // micro-tile col group
    const int ty = tid >> 4;   // micro-tile row group
    const int m0 = blockIdx.y * BM;
    const int n0 = blockIdx.x * BN;

    // staging indices: A tile 64 rows x 16 k (one float4/thread),
    //                  B tile 16 k x 64 cols (one float4/thread)
    const int arow = tid >> 2;          // 0..63
    const int acol = (tid & 3) << 2;    // 0,4,8,12
    const int brow = tid >> 4;          // 0..15
    const int bcol = (tid & 15) << 2;   // 0..60

    const float* vptr = V + (size_t)(m0 + arow) * kVIS + acol;
    const float* wptr = Wm + (size_t)brow * kHID + n0 + bcol;

    float acc[4][4] = {};

    for (int k0 = 0; k0 < kVIS; k0 += BK) {
        const float4 a4 = *(const float4*)(vptr + k0);
        const float4 b4 = *(const float4*)(wptr + (size_t)k0 * kHID);
        __syncthreads();  // previous iteration's reads complete before overwrite
        As[acol + 0][arow] = a4.x;
        As[acol + 1][arow] = a4.y;
        As[acol + 2][arow] = a4.z;
        As[acol + 3][arow] = a4.w;
        *(float4*)&Bs[brow][bcol] = b4;
        __syncthreads();
#pragma unroll
        for (int k = 0; k < BK; ++k) {
            const float4 av = *(const float4*)&As[k][ty << 2];
            const float4 bv = *(const float4*)&Bs[k][tx << 2];
            const float a[4] = {av.x, av.y, av.z, av.w};
            const float b[4] = {bv.x, bv.y, bv.z, bv.w};
#pragma unroll
            for (int i = 0; i < 4; ++i)
#pragma unroll
                for (int j = 0; j < 4; ++j) acc[i][j] += a[i] * b[j];
        }
    }

#pragma unroll
    for (int i = 0; i < 4; ++i) {
        const int row = m0 + (ty << 2) + i;
        const int col = n0 + (tx << 2);
        const float4 cv = *(const float4*)(cvec + col);
        float4 o;
        o.x = acc[i][0] + cv.x;
        o.y = acc[i][1] + cv.y;
        o.z = acc[i][2] + cv.z;
        o.w = acc[i][3] + cv.w;
        *(float4*)(pre + (size_t)row * kHID + col) = o;
    }
}

// ---------------- Kernel 2: F, softmax, argmax, one-hot ----------------
// Each block handles RB=4 batch rows. pre rows staged in LDS (16 KB).
// Wave w owns classes [16w, 16w+16); lane strides hidden dim by 64
// (coalesced U reads; U = 256 KB stays L2-hot).
constexpr int RB = 4;

__device__ __forceinline__ float softplus_f(float x) {
    // stable: max(x,0) + log1p(exp(-|x|)); exp underflow -> log(1) = 0, exact.
    return fmaxf(x, 0.f) + __logf(1.f + __expf(-fabsf(x)));
}

__global__ __launch_bounds__(256) void classify(const float* __restrict__ pre,
                                                const float* __restrict__ U,
                                                const float* __restrict__ dvec,
                                                float* __restrict__ out) {
    __shared__ float preS[RB][kHID];
    __shared__ float Fs[RB][kCLS];
    const int tid  = threadIdx.x;
    const int lane = tid & 63;
    const int wave = tid >> 6;  // 0..3
    const int b0   = blockIdx.x * RB;

    // stage RB pre rows into LDS
    const float4* src = (const float4*)(pre + (size_t)b0 * kHID);
    float4* dst = (float4*)preS;
    for (int i = tid; i < RB * kHID / 4; i += 256) dst[i] = src[i];
    __syncthreads();

    for (int yi = 0; yi < 16; ++yi) {
        const int y = (wave << 4) + yi;
        const float* Uy = U + (size_t)y * kHID;
        float a0 = 0.f, a1 = 0.f, a2 = 0.f, a3 = 0.f;
#pragma unroll
        for (int it = 0; it < kHID / 64; ++it) {
            const int j = lane + (it << 6);
            const float u = Uy[j];
            a0 += softplus_f(preS[0][j] + u);
            a1 += softplus_f(preS[1][j] + u);
            a2 += softplus_f(preS[2][j] + u);
            a3 += softplus_f(preS[3][j] + u);
        }
        // reduce lane partials across the wave in double (F ~ 2e4, class gaps
        // can be small; double reduction removes our reduction-order noise)
        double d0 = a0, d1 = a1, d2 = a2, d3 = a3;
#pragma unroll
        for (int off = 32; off; off >>= 1) {
            d0 += __shfl_xor(d0, off);
            d1 += __shfl_xor(d1, off);
            d2 += __shfl_xor(d2, off);
            d3 += __shfl_xor(d3, off);
        }
        if (lane == 0) {
            const float dy = dvec[y];
            Fs[0][y] = (float)d0 + dy;
            Fs[1][y] = (float)d1 + dy;
            Fs[2][y] = (float)d2 + dy;
            Fs[3][y] = (float)d3 + dy;
        }
    }
    __syncthreads();

    // wave r -> batch row b0+r; lane -> class (kCLS == 64 == wave width)
    const int r = wave;
    const float F = Fs[r][lane];
    float m = F;
    int mi = lane;
#pragma unroll
    for (int off = 32; off; off >>= 1) {
        const float om = __shfl_xor(m, off);
        const int   oi = __shfl_xor(mi, off);
        if (om > m || (om == m && oi < mi)) { m = om; mi = oi; }  // first-index tie-break (jnp.argmax)
    }
    const float e = __expf(F - m);
    float s = e;
#pragma unroll
    for (int off = 32; off; off >>= 1) s += __shfl_xor(s, off);
    const float p = e / s;
    const int row = b0 + r;
    out[(size_t)row * kCLS + lane] = p;                                   // class_probs
    out[(size_t)kB * kCLS + (size_t)row * kCLS + lane] = (lane == mi) ? 1.0f : 0.0f;  // one_hot
}

extern "C" void kernel_launch(void* const* d_in, const int* in_sizes, int n_in,
                              void* d_out, int out_size, void* d_ws, size_t ws_size,
                              hipStream_t stream) {
    const float* v  = (const float*)d_in[0];
    const float* W  = (const float*)d_in[1];
    const float* c  = (const float*)d_in[2];
    const float* d  = (const float*)d_in[3];
    const float* U  = (const float*)d_in[4];
    float* out = (float*)d_out;
    float* pre = (float*)d_ws;  // 2048*1024*4 = 8 MB scratch

    dim3 g1(kHID / BN, kB / BM);  // (16, 32)
    gemm_vw<<<g1, 256, 0, stream>>>(v, W, c, pre);
    classify<<<kB / RB, 256, 0, stream>>>(pre, U, d, out);
}

// Round 2
// 163.844 us; speedup vs baseline: 1.6483x; 1.6483x over previous
//
#include <hip/hip_runtime.h>

// Problem sizes (fixed by the reference)
constexpr int kB    = 2048;  // batch
constexpr int kVIS  = 2048;  // visible units (GEMM K)
constexpr int kHID  = 1024;  // hidden units (GEMM N)
constexpr int kCLS  = 64;    // classes
constexpr float kLog2e = 1.4426950408889634f;

typedef __attribute__((ext_vector_type(8))) short bf16x8;
typedef __attribute__((ext_vector_type(4))) float f32x4;

__device__ __forceinline__ unsigned short f2bf(float x) {
    // round-to-nearest-even f32 -> bf16 (finite inputs only)
    unsigned u = __float_as_uint(x);
    u += 0x7fffu + ((u >> 16) & 1u);
    return (unsigned short)(u >> 16);
}
__device__ __forceinline__ float bf2f(unsigned short h) {
    return __uint_as_float(((unsigned)h) << 16);
}

// ---------------- Prep 1: v -> vh, vl (bf16 split, same layout) ----------------
__global__ __launch_bounds__(256) void split_v(const float* __restrict__ x,
                                               unsigned short* __restrict__ hi,
                                               unsigned short* __restrict__ lo) {
    const int i = (blockIdx.x * 256 + threadIdx.x) * 4;
    const float4 xv = *(const float4*)(x + i);
    ushort4 h, l;
    h.x = f2bf(xv.x); l.x = f2bf(xv.x - bf2f(h.x));
    h.y = f2bf(xv.y); l.y = f2bf(xv.y - bf2f(h.y));
    h.z = f2bf(xv.z); l.z = f2bf(xv.z - bf2f(h.z));
    h.w = f2bf(xv.w); l.w = f2bf(xv.w - bf2f(h.w));
    *(ushort4*)(hi + i) = h;
    *(ushort4*)(lo + i) = l;
}

// ---------------- Prep 2: W[k][n] -> Wt_h/Wt_l[n][k] (bf16 split + transpose) ----------------
__global__ __launch_bounds__(256) void split_w_t(const float* __restrict__ W,
                                                 unsigned short* __restrict__ th,
                                                 unsigned short* __restrict__ tl) {
    __shared__ float T[32][33];
    const int n0 = blockIdx.x * 32, k0 = blockIdx.y * 32;
    const int c = threadIdx.x & 31, r0 = threadIdx.x >> 5;
#pragma unroll
    for (int p = 0; p < 4; ++p) {
        const int r = r0 + p * 8;
        T[r][c] = W[(size_t)(k0 + r) * kHID + n0 + c];
    }
    __syncthreads();
#pragma unroll
    for (int p = 0; p < 4; ++p) {
        const int rr = r0 + p * 8;          // n offset
        const float v = T[c][rr];           // = W[k0+c][n0+rr]
        const unsigned short h = f2bf(v);
        const unsigned short l = f2bf(v - bf2f(h));
        const size_t o = (size_t)(n0 + rr) * kVIS + k0 + c;
        th[o] = h;
        tl[o] = l;
    }
}

// ---------------- Prep 3: U[y][j] -> Ut[j][y] scaled by log2e ----------------
__global__ __launch_bounds__(256) void scale_u_t(const float* __restrict__ U,
                                                 float* __restrict__ Ut) {
    const int id = blockIdx.x * 256 + threadIdx.x;  // 0..65535
    const int j = id >> 6, y = id & 63;
    Ut[id] = U[(size_t)y * kHID + j] * kLog2e;
}

// ---------------- Kernel 1: pre' = (v@W + c) * log2e via split-bf16 MFMA ----------------
// 64x64 tile, 4 waves, each wave a 32x32 quadrant as 2x2 mfma_f32_16x16x32_bf16 tiles.
// 3 MFMA products per tile (hh, hl, lh); ll dropped (~2^-18 relative).
// LDS rows padded to 72 bf16 -> 2-way bank aliasing (free per m136).
constexpr int LDK = 72;

__global__ __launch_bounds__(256) void gemm_mfma(const unsigned short* __restrict__ vh,
                                                 const unsigned short* __restrict__ vl,
                                                 const unsigned short* __restrict__ wth,
                                                 const unsigned short* __restrict__ wtl,
                                                 const float* __restrict__ cvec,
                                                 float* __restrict__ pre) {
    __shared__ unsigned short Ah[64 * LDK], Al[64 * LDK], Bh[64 * LDK], Bl[64 * LDK];
    const int tid = threadIdx.x;
    const int lane = tid & 63, wave = tid >> 6;
    const int m0 = blockIdx.y * 64, n0 = blockIdx.x * 64;
    const int wm = (wave >> 1) * 32, wn = (wave & 1) * 32;

    // staging: thread covers 2 slots; slot s -> row s>>3 (0..63), col-group (s&7)*8
    const int r0 = tid >> 3, r1 = r0 + 32;
    const int cg = (tid & 7) * 8;
    const size_t ga0 = (size_t)(m0 + r0) * kVIS + cg;
    const size_t ga1 = (size_t)(m0 + r1) * kVIS + cg;
    const size_t gb0 = (size_t)(n0 + r0) * kVIS + cg;
    const size_t gb1 = (size_t)(n0 + r1) * kVIS + cg;
    const int l0 = r0 * LDK + cg, l1 = r1 * LDK + cg;

    // fragment addressing: A[m=lane&15][k=(lane>>4)*8+j], B[n=lane&15][k=(lane>>4)*8+j]
    const int fm = lane & 15, fq = lane >> 4;
    const int fa0 = (wm + fm) * LDK + fq * 8;
    const int fa1 = (wm + 16 + fm) * LDK + fq * 8;
    const int fb0 = (wn + fm) * LDK + fq * 8;
    const int fb1 = (wn + 16 + fm) * LDK + fq * 8;

    f32x4 acc[2][2] = {};

    for (int k0 = 0; k0 < kVIS; k0 += 64) {
        const bf16x8 rah0 = *(const bf16x8*)(vh + ga0 + k0);
        const bf16x8 rah1 = *(const bf16x8*)(vh + ga1 + k0);
        const bf16x8 ral0 = *(const bf16x8*)(vl + ga0 + k0);
        const bf16x8 ral1 = *(const bf16x8*)(vl + ga1 + k0);
        const bf16x8 rbh0 = *(const bf16x8*)(wth + gb0 + k0);
        const bf16x8 rbh1 = *(const bf16x8*)(wth + gb1 + k0);
        const bf16x8 rbl0 = *(const bf16x8*)(wtl + gb0 + k0);
        const bf16x8 rbl1 = *(const bf16x8*)(wtl + gb1 + k0);
        __syncthreads();  // prior compute done reading LDS
        *(bf16x8*)(Ah + l0) = rah0; *(bf16x8*)(Ah + l1) = rah1;
        *(bf16x8*)(Al + l0) = ral0; *(bf16x8*)(Al + l1) = ral1;
        *(bf16x8*)(Bh + l0) = rbh0; *(bf16x8*)(Bh + l1) = rbh1;
        *(bf16x8*)(Bl + l0) = rbl0; *(bf16x8*)(Bl + l1) = rbl1;
        __syncthreads();
#pragma unroll
        for (int kk = 0; kk < 64; kk += 32) {
            const bf16x8 ah0 = *(const bf16x8*)(Ah + fa0 + kk);
            const bf16x8 ah1 = *(const bf16x8*)(Ah + fa1 + kk);
            const bf16x8 al0 = *(const bf16x8*)(Al + fa0 + kk);
            const bf16x8 al1 = *(const bf16x8*)(Al + fa1 + kk);
            const bf16x8 bh0 = *(const bf16x8*)(Bh + fb0 + kk);
            const bf16x8 bh1 = *(const bf16x8*)(Bh + fb1 + kk);
            const bf16x8 bl0 = *(const bf16x8*)(Bl + fb0 + kk);
            const bf16x8 bl1 = *(const bf16x8*)(Bl + fb1 + kk);
            acc[0][0] = __builtin_amdgcn_mfma_f32_16x16x32_bf16(ah0, bh0, acc[0][0], 0, 0, 0);
            acc[0][0] = __builtin_amdgcn_mfma_f32_16x16x32_bf16(ah0, bl0, acc[0][0], 0, 0, 0);
            acc[0][0] = __builtin_amdgcn_mfma_f32_16x16x32_bf16(al0, bh0, acc[0][0], 0, 0, 0);
            acc[0][1] = __builtin_amdgcn_mfma_f32_16x16x32_bf16(ah0, bh1, acc[0][1], 0, 0, 0);
            acc[0][1] = __builtin_amdgcn_mfma_f32_16x16x32_bf16(ah0, bl1, acc[0][1], 0, 0, 0);
            acc[0][1] = __builtin_amdgcn_mfma_f32_16x16x32_bf16(al0, bh1, acc[0][1], 0, 0, 0);
            acc[1][0] = __builtin_amdgcn_mfma_f32_16x16x32_bf16(ah1, bh0, acc[1][0], 0, 0, 0);
            acc[1][0] = __builtin_amdgcn_mfma_f32_16x16x32_bf16(ah1, bl0, acc[1][0], 0, 0, 0);
            acc[1][0] = __builtin_amdgcn_mfma_f32_16x16x32_bf16(al1, bh0, acc[1][0], 0, 0, 0);
            acc[1][1] = __builtin_amdgcn_mfma_f32_16x16x32_bf16(ah1, bh1, acc[1][1], 0, 0, 0);
            acc[1][1] = __builtin_amdgcn_mfma_f32_16x16x32_bf16(ah1, bl1, acc[1][1], 0, 0, 0);
            acc[1][1] = __builtin_amdgcn_mfma_f32_16x16x32_bf16(al1, bh1, acc[1][1], 0, 0, 0);
        }
    }

    // epilogue: C/D layout col=lane&15, row=(lane>>4)*4+reg; scale to log2 domain
#pragma unroll
    for (int j = 0; j < 2; ++j) {
        const int col = n0 + wn + j * 16 + fm;
        const float cv = cvec[col];
#pragma unroll
        for (int i = 0; i < 2; ++i) {
            const int rbase = m0 + wm + i * 16 + fq * 4;
#pragma unroll
            for (int r = 0; r < 4; ++r) {
                pre[(size_t)(rbase + r) * kHID + col] = (acc[i][j][r] + cv) * kLog2e;
            }
        }
    }
}

// ---------------- Kernel 2 (v2): lane=class, wave=batch-row ----------------
// pre' and Ut are prescaled by log2e: softplus(x)*log2e = max(x',0) + log2(1+2^-|x'|).
// Lane y accumulates its own class in double (no cross-lane reduction for F).
__global__ __launch_bounds__(256) void classify2(const float* __restrict__ preS_g,
                                                 const float* __restrict__ Ut,
                                                 const float* __restrict__ dvec,
                                                 float* __restrict__ out) {
    __shared__ float ps[4][kHID];
    const int tid = threadIdx.x;
    const int lane = tid & 63, wave = tid >> 6;
    const int b0 = blockIdx.x * 4;

    const float4* src = (const float4*)(preS_g + (size_t)b0 * kHID);
    float4* dst = (float4*)ps;
    for (int i = tid; i < 4 * kHID / 4; i += 256) dst[i] = src[i];
    __syncthreads();

    const float* prow = ps[wave];
    double acc = 0.0;
#pragma unroll 16
    for (int j = 0; j < kHID; ++j) {
        const float u = Ut[j * kCLS + lane];   // coalesced, L2-hot
        const float t = prow[j] + u;           // LDS broadcast read (free)
        const float e = __builtin_amdgcn_exp2f(-fabsf(t));
        const float sp = fmaxf(t, 0.f) + __builtin_amdgcn_logf(1.f + e);
        acc += (double)sp;
    }
    const float G = (float)acc + dvec[lane] * kLog2e;  // log2-domain logit

    // wave softmax + argmax over 64 lanes (classes)
    float m = G;
    int mi = lane;
#pragma unroll
    for (int off = 32; off; off >>= 1) {
        const float om = __shfl_xor(m, off);
        const int   oi = __shfl_xor(mi, off);
        if (om > m || (om == m && oi < mi)) { m = om; mi = oi; }  // first-index tie-break
    }
    const float e2 = __builtin_amdgcn_exp2f(G - m);
    float s = e2;
#pragma unroll
    for (int off = 32; off; off >>= 1) s += __shfl_xor(s, off);
    const float p = e2 / s;
    const int row = b0 + wave;
    out[(size_t)row * kCLS + lane] = p;
    out[(size_t)kB * kCLS + (size_t)row * kCLS + lane] = (lane == mi) ? 1.0f : 0.0f;
}

// ================= Fallback (round-1, known-passing) if ws is too small =================
constexpr int BM = 64, BN = 64, BK = 16;

__global__ __launch_bounds__(256) void gemm_vw(const float* __restrict__ V,
                                               const float* __restrict__ Wm,
                                               const float* __restrict__ cvec,
                                               float* __restrict__ pre) {
    __shared__ float As[BK][BM + 4];
    __shared__ float Bs[BK][BN + 4];
    const int tid = threadIdx.x;
    const int tx = tid & 15, ty = tid >> 4;
    const int m0 = blockIdx.y * BM, n0 = blockIdx.x * BN;
    const int arow = tid >> 2, acol = (tid & 3) << 2;
    const int brow = tid >> 4, bcol = (tid & 15) << 2;
    const float* vptr = V + (size_t)(m0 + arow) * kVIS + acol;
    const float* wptr = Wm + (size_t)brow * kHID + n0 + bcol;
    float acc[4][4] = {};
    for (int k0 = 0; k0 < kVIS; k0 += BK) {
        const float4 a4 = *(const float4*)(vptr + k0);
        const float4 b4 = *(const float4*)(wptr + (size_t)k0 * kHID);
        __syncthreads();
        As[acol + 0][arow] = a4.x; As[acol + 1][arow] = a4.y;
        As[acol + 2][arow] = a4.z; As[acol + 3][arow] = a4.w;
        *(float4*)&Bs[brow][bcol] = b4;
        __syncthreads();
#pragma unroll
        for (int k = 0; k < BK; ++k) {
            const float4 av = *(const float4*)&As[k][ty << 2];
            const float4 bv = *(const float4*)&Bs[k][tx << 2];
            const float a[4] = {av.x, av.y, av.z, av.w};
            const float b[4] = {bv.x, bv.y, bv.z, bv.w};
#pragma unroll
            for (int i = 0; i < 4; ++i)
#pragma unroll
                for (int j = 0; j < 4; ++j) acc[i][j] += a[i] * b[j];
        }
    }
#pragma unroll
    for (int i = 0; i < 4; ++i) {
        const int row = m0 + (ty << 2) + i;
        const int col = n0 + (tx << 2);
        const float4 cv = *(const float4*)(cvec + col);
        float4 o;
        o.x = acc[i][0] + cv.x; o.y = acc[i][1] + cv.y;
        o.z = acc[i][2] + cv.z; o.w = acc[i][3] + cv.w;
        *(float4*)(pre + (size_t)row * kHID + col) = o;
    }
}

__device__ __forceinline__ float softplus_f(float x) {
    return fmaxf(x, 0.f) + __logf(1.f + __expf(-fabsf(x)));
}

__global__ __launch_bounds__(256) void classify(const float* __restrict__ pre,
                                                const float* __restrict__ U,
                                                const float* __restrict__ dvec,
                                                float* __restrict__ out) {
    __shared__ float preS[4][kHID];
    __shared__ float Fs[4][kCLS];
    const int tid = threadIdx.x;
    const int lane = tid & 63, wave = tid >> 6;
    const int b0 = blockIdx.x * 4;
    const float4* src = (const float4*)(pre + (size_t)b0 * kHID);
    float4* dst = (float4*)preS;
    for (int i = tid; i < kHID; i += 256) dst[i] = src[i];
    __syncthreads();
    for (int yi = 0; yi < 16; ++yi) {
        const int y = (wave << 4) + yi;
        const float* Uy = U + (size_t)y * kHID;
        float a0 = 0.f, a1 = 0.f, a2 = 0.f, a3 = 0.f;
#pragma unroll
        for (int it = 0; it < kHID / 64; ++it) {
            const int j = lane + (it << 6);
            const float u = Uy[j];
            a0 += softplus_f(preS[0][j] + u);
            a1 += softplus_f(preS[1][j] + u);
            a2 += softplus_f(preS[2][j] + u);
            a3 += softplus_f(preS[3][j] + u);
        }
        double d0 = a0, d1 = a1, d2 = a2, d3 = a3;
#pragma unroll
        for (int off = 32; off; off >>= 1) {
            d0 += __shfl_xor(d0, off); d1 += __shfl_xor(d1, off);
            d2 += __shfl_xor(d2, off); d3 += __shfl_xor(d3, off);
        }
        if (lane == 0) {
            const float dy = dvec[y];
            Fs[0][y] = (float)d0 + dy; Fs[1][y] = (float)d1 + dy;
            Fs[2][y] = (float)d2 + dy; Fs[3][y] = (float)d3 + dy;
        }
    }
    __syncthreads();
    const float F = Fs[wave][lane];
    float m = F; int mi = lane;
#pragma unroll
    for (int off = 32; off; off >>= 1) {
        const float om = __shfl_xor(m, off);
        const int oi = __shfl_xor(mi, off);
        if (om > m || (om == m && oi < mi)) { m = om; mi = oi; }
    }
    const float e = __expf(F - m);
    float s = e;
#pragma unroll
    for (int off = 32; off; off >>= 1) s += __shfl_xor(s, off);
    const int row = b0 + wave;
    out[(size_t)row * kCLS + lane] = e / s;
    out[(size_t)kB * kCLS + (size_t)row * kCLS + lane] = (lane == mi) ? 1.0f : 0.0f;
}

extern "C" void kernel_launch(void* const* d_in, const int* in_sizes, int n_in,
                              void* d_out, int out_size, void* d_ws, size_t ws_size,
                              hipStream_t stream) {
    const float* v = (const float*)d_in[0];
    const float* W = (const float*)d_in[1];
    const float* c = (const float*)d_in[2];
    const float* d = (const float*)d_in[3];
    const float* U = (const float*)d_in[4];
    float* out = (float*)d_out;
    char* ws = (char*)d_ws;

    // ws layout: pre 8MB | vh 8MB | vl 8MB | Wt_h 4MB | Wt_l 4MB | Ut 256KB
    const size_t need = 33816576;
    if (ws_size >= need) {
        float* pre = (float*)ws;
        unsigned short* vh  = (unsigned short*)(ws + 8388608);
        unsigned short* vl  = (unsigned short*)(ws + 16777216);
        unsigned short* wth = (unsigned short*)(ws + 25165824);
        unsigned short* wtl = (unsigned short*)(ws + 29360128);
        float* Ut = (float*)(ws + 33554432);
        split_v<<<4096, 256, 0, stream>>>(v, vh, vl);
        split_w_t<<<dim3(kHID / 32, kVIS / 32), 256, 0, stream>>>(W, wth, wtl);
        scale_u_t<<<kHID * kCLS / 256, 256, 0, stream>>>(U, Ut);
        gemm_mfma<<<dim3(kHID / 64, kB / 64), 256, 0, stream>>>(vh, vl, wth, wtl, c, pre);
        classify2<<<kB / 4, 256, 0, stream>>>(pre, Ut, d, out);
    } else {
        float* pre = (float*)ws;
        gemm_vw<<<dim3(kHID / BN, kB / BM), 256, 0, stream>>>(v, W, c, pre);
        classify<<<kB / 4, 256, 0, stream>>>(pre, U, d, out);
    }
}

// Round 3
// 144.114 us; speedup vs baseline: 1.8739x; 1.1369x over previous
//
#include <hip/hip_runtime.h>

// Problem sizes (fixed by the reference)
constexpr int kB    = 2048;  // batch
constexpr int kVIS  = 2048;  // visible units (GEMM K)
constexpr int kHID  = 1024;  // hidden units (GEMM N)
constexpr int kCLS  = 64;    // classes
constexpr float kLog2e = 1.4426950408889634f;

typedef __attribute__((ext_vector_type(8))) short bf16x8;
typedef __attribute__((ext_vector_type(4))) float f32x4;

__device__ __forceinline__ unsigned short f2bf(float x) {
    unsigned u = __float_as_uint(x);
    u += 0x7fffu + ((u >> 16) & 1u);
    return (unsigned short)(u >> 16);
}
__device__ __forceinline__ float bf2f(unsigned short h) {
    return __uint_as_float(((unsigned)h) << 16);
}

// ---------------- Prep (merged): split v, split+transpose W, scale+transpose U ----------
// blocks [0,4096): split_v ; [4096,6144): split_w_t ; [6144,6400): scale_u_t
__global__ __launch_bounds__(256) void prep_all(const float* __restrict__ v,
                                                const float* __restrict__ W,
                                                const float* __restrict__ U,
                                                unsigned short* __restrict__ vh,
                                                unsigned short* __restrict__ vl,
                                                unsigned short* __restrict__ wth,
                                                unsigned short* __restrict__ wtl,
                                                float* __restrict__ Ut) {
    __shared__ float T[32][33];
    const int bx = blockIdx.x;
    if (bx < 4096) {
        const int i = (bx * 256 + threadIdx.x) * 4;
        const float4 xv = *(const float4*)(v + i);
        ushort4 h, l;
        h.x = f2bf(xv.x); l.x = f2bf(xv.x - bf2f(h.x));
        h.y = f2bf(xv.y); l.y = f2bf(xv.y - bf2f(h.y));
        h.z = f2bf(xv.z); l.z = f2bf(xv.z - bf2f(h.z));
        h.w = f2bf(xv.w); l.w = f2bf(xv.w - bf2f(h.w));
        *(ushort4*)(vh + i) = h;
        *(ushort4*)(vl + i) = l;
    } else if (bx < 6144) {
        const int b = bx - 4096;
        const int n0 = (b & 31) * 32, k0 = (b >> 5) * 32;
        const int c = threadIdx.x & 31, r0 = threadIdx.x >> 5;
#pragma unroll
        for (int p = 0; p < 4; ++p) {
            const int r = r0 + p * 8;
            T[r][c] = W[(size_t)(k0 + r) * kHID + n0 + c];
        }
        __syncthreads();
#pragma unroll
        for (int p = 0; p < 4; ++p) {
            const int rr = r0 + p * 8;          // n offset
            const float x = T[c][rr];           // = W[k0+c][n0+rr]
            const unsigned short h = f2bf(x);
            const unsigned short l = f2bf(x - bf2f(h));
            const size_t o = (size_t)(n0 + rr) * kVIS + k0 + c;
            wth[o] = h;
            wtl[o] = l;
        }
    } else {
        const int id = (bx - 6144) * 256 + threadIdx.x;  // 0..65535
        const int j = id >> 6, y = id & 63;
        Ut[id] = U[(size_t)y * kHID + j] * kLog2e;
    }
}

// ---------------- Fused kernel: split-bf16 MFMA GEMM + softplus partial-F epilogue ------
// 64x64 tile, 4 waves (32x32 quadrants, 2x2 of mfma_f32_16x16x32_bf16, 3 products).
// Epilogue: pre-tile -> LDS (log2-domain, +c), Ut block -> LDS; wave owns 16 rows,
// lane = class; per 64-j chunk: relu-sum + log2(prod(1+2^-|t|)) -> Fpart[chunk][row][y].
constexpr int LDK = 72;

__global__ __launch_bounds__(256) void gemm_fused(const unsigned short* __restrict__ vh,
                                                  const unsigned short* __restrict__ vl,
                                                  const unsigned short* __restrict__ wth,
                                                  const unsigned short* __restrict__ wtl,
                                                  const float* __restrict__ cvec,
                                                  const float* __restrict__ Ut,
                                                  float* __restrict__ Fpart) {
    __shared__ __align__(16) union SMem {
        unsigned short stage[4][64 * LDK];               // Ah, Al, Bh, Bl  (36864 B)
        struct { float ps[64][64]; float uts[64][64]; } epi;  // 32768 B, overlays stage
    } smem;
    unsigned short* Ah = smem.stage[0];
    unsigned short* Al = smem.stage[1];
    unsigned short* Bh = smem.stage[2];
    unsigned short* Bl = smem.stage[3];

    const int tid = threadIdx.x;
    const int lane = tid & 63, wave = tid >> 6;
    const int m0 = blockIdx.y * 64, n0 = blockIdx.x * 64;
    const int wm = (wave >> 1) * 32, wn = (wave & 1) * 32;

    const int r0 = tid >> 3, r1 = r0 + 32;
    const int cg = (tid & 7) * 8;
    const size_t ga0 = (size_t)(m0 + r0) * kVIS + cg;
    const size_t ga1 = (size_t)(m0 + r1) * kVIS + cg;
    const size_t gb0 = (size_t)(n0 + r0) * kVIS + cg;
    const size_t gb1 = (size_t)(n0 + r1) * kVIS + cg;
    const int l0 = r0 * LDK + cg, l1 = r1 * LDK + cg;

    const int fm = lane & 15, fq = lane >> 4;
    const int fa0 = (wm + fm) * LDK + fq * 8;
    const int fa1 = (wm + 16 + fm) * LDK + fq * 8;
    const int fb0 = (wn + fm) * LDK + fq * 8;
    const int fb1 = (wn + 16 + fm) * LDK + fq * 8;

    f32x4 acc[2][2] = {};

    for (int k0 = 0; k0 < kVIS; k0 += 64) {
        const bf16x8 rah0 = *(const bf16x8*)(vh + ga0 + k0);
        const bf16x8 rah1 = *(const bf16x8*)(vh + ga1 + k0);
        const bf16x8 ral0 = *(const bf16x8*)(vl + ga0 + k0);
        const bf16x8 ral1 = *(const bf16x8*)(vl + ga1 + k0);
        const bf16x8 rbh0 = *(const bf16x8*)(wth + gb0 + k0);
        const bf16x8 rbh1 = *(const bf16x8*)(wth + gb1 + k0);
        const bf16x8 rbl0 = *(const bf16x8*)(wtl + gb0 + k0);
        const bf16x8 rbl1 = *(const bf16x8*)(wtl + gb1 + k0);
        __syncthreads();
        *(bf16x8*)(Ah + l0) = rah0; *(bf16x8*)(Ah + l1) = rah1;
        *(bf16x8*)(Al + l0) = ral0; *(bf16x8*)(Al + l1) = ral1;
        *(bf16x8*)(Bh + l0) = rbh0; *(bf16x8*)(Bh + l1) = rbh1;
        *(bf16x8*)(Bl + l0) = rbl0; *(bf16x8*)(Bl + l1) = rbl1;
        __syncthreads();
#pragma unroll
        for (int kk = 0; kk < 64; kk += 32) {
            const bf16x8 ah0 = *(const bf16x8*)(Ah + fa0 + kk);
            const bf16x8 ah1 = *(const bf16x8*)(Ah + fa1 + kk);
            const bf16x8 al0 = *(const bf16x8*)(Al + fa0 + kk);
            const bf16x8 al1 = *(const bf16x8*)(Al + fa1 + kk);
            const bf16x8 bh0 = *(const bf16x8*)(Bh + fb0 + kk);
            const bf16x8 bh1 = *(const bf16x8*)(Bh + fb1 + kk);
            const bf16x8 bl0 = *(const bf16x8*)(Bl + fb0 + kk);
            const bf16x8 bl1 = *(const bf16x8*)(Bl + fb1 + kk);
            acc[0][0] = __builtin_amdgcn_mfma_f32_16x16x32_bf16(ah0, bh0, acc[0][0], 0, 0, 0);
            acc[0][0] = __builtin_amdgcn_mfma_f32_16x16x32_bf16(ah0, bl0, acc[0][0], 0, 0, 0);
            acc[0][0] = __builtin_amdgcn_mfma_f32_16x16x32_bf16(al0, bh0, acc[0][0], 0, 0, 0);
            acc[0][1] = __builtin_amdgcn_mfma_f32_16x16x32_bf16(ah0, bh1, acc[0][1], 0, 0, 0);
            acc[0][1] = __builtin_amdgcn_mfma_f32_16x16x32_bf16(ah0, bl1, acc[0][1], 0, 0, 0);
            acc[0][1] = __builtin_amdgcn_mfma_f32_16x16x32_bf16(al0, bh1, acc[0][1], 0, 0, 0);
            acc[1][0] = __builtin_amdgcn_mfma_f32_16x16x32_bf16(ah1, bh0, acc[1][0], 0, 0, 0);
            acc[1][0] = __builtin_amdgcn_mfma_f32_16x16x32_bf16(ah1, bl0, acc[1][0], 0, 0, 0);
            acc[1][0] = __builtin_amdgcn_mfma_f32_16x16x32_bf16(al1, bh0, acc[1][0], 0, 0, 0);
            acc[1][1] = __builtin_amdgcn_mfma_f32_16x16x32_bf16(ah1, bh1, acc[1][1], 0, 0, 0);
            acc[1][1] = __builtin_amdgcn_mfma_f32_16x16x32_bf16(ah1, bl1, acc[1][1], 0, 0, 0);
            acc[1][1] = __builtin_amdgcn_mfma_f32_16x16x32_bf16(al1, bh1, acc[1][1], 0, 0, 0);
        }
    }

    // ---- epilogue: pre-tile to LDS (log2 domain), Ut block to LDS ----
    __syncthreads();  // all waves done reading stage LDS
#pragma unroll
    for (int j = 0; j < 2; ++j) {
        const int col = wn + j * 16 + fm;              // local hid col 0..63
        const float cv = cvec[n0 + col];
#pragma unroll
        for (int i = 0; i < 2; ++i) {
            const int rbase = wm + i * 16 + fq * 4;    // local row
#pragma unroll
            for (int r = 0; r < 4; ++r)
                smem.epi.ps[rbase + r][col] = (acc[i][j][r] + cv) * kLog2e;
        }
    }
    {
        const float4* src = (const float4*)(Ut + (size_t)n0 * kCLS);
        float4* dst = (float4*)smem.epi.uts;
        for (int i = tid; i < 64 * 64 / 4; i += 256) dst[i] = src[i];
    }
    __syncthreads();

    // wave owns rows [wave*16, wave*16+16); lane = class
    for (int rr = 0; rr < 16; ++rr) {
        const int row = wave * 16 + rr;
        float relu = 0.f;
        float prod = 1.f;   // max 2^64 (all t==0), fits fp32
#pragma unroll 16
        for (int jj = 0; jj < 64; ++jj) {
            const float t = smem.epi.ps[row][jj] + smem.epi.uts[jj][lane];
            const float e = __builtin_amdgcn_exp2f(-fabsf(t));  // 2^-|t|
            prod = __builtin_fmaf(prod, e, prod);               // prod *= (1+e)
            relu += fmaxf(t, 0.f);
        }
        const float contrib = relu + __builtin_amdgcn_logf(prod);  // log2 domain
        Fpart[((size_t)blockIdx.x * kB + m0 + row) * kCLS + lane] = contrib;
    }
}

// ---------------- Final: sum 16 partials (double), softmax, argmax, one-hot ------------
__global__ __launch_bounds__(256) void softmax_final(const float* __restrict__ Fpart,
                                                     const float* __restrict__ dvec,
                                                     float* __restrict__ out) {
    const int tid = threadIdx.x;
    const int lane = tid & 63, wave = tid >> 6;
    const int row = blockIdx.x * 4 + wave;
    double s = 0.0;
#pragma unroll
    for (int k = 0; k < kHID / 64; ++k)
        s += (double)Fpart[((size_t)k * kB + row) * kCLS + lane];
    const float G = (float)s + dvec[lane] * kLog2e;  // log2-domain logit

    float m = G;
    int mi = lane;
#pragma unroll
    for (int off = 32; off; off >>= 1) {
        const float om = __shfl_xor(m, off);
        const int   oi = __shfl_xor(mi, off);
        if (om > m || (om == m && oi < mi)) { m = om; mi = oi; }  // first-index tie-break
    }
    const float e2 = __builtin_amdgcn_exp2f(G - m);
    float ssum = e2;
#pragma unroll
    for (int off = 32; off; off >>= 1) ssum += __shfl_xor(ssum, off);
    out[(size_t)row * kCLS + lane] = e2 / ssum;
    out[(size_t)kB * kCLS + (size_t)row * kCLS + lane] = (lane == mi) ? 1.0f : 0.0f;
}

// ================= Fallback (round-1, known-passing) if ws is too small =================
constexpr int BM = 64, BN = 64, BK = 16;

__global__ __launch_bounds__(256) void gemm_vw(const float* __restrict__ V,
                                               const float* __restrict__ Wm,
                                               const float* __restrict__ cvec,
                                               float* __restrict__ pre) {
    __shared__ float As[BK][BM + 4];
    __shared__ float Bs[BK][BN + 4];
    const int tid = threadIdx.x;
    const int tx = tid & 15, ty = tid >> 4;
    const int m0 = blockIdx.y * BM, n0 = blockIdx.x * BN;
    const int arow = tid >> 2, acol = (tid & 3) << 2;
    const int brow = tid >> 4, bcol = (tid & 15) << 2;
    const float* vptr = V + (size_t)(m0 + arow) * kVIS + acol;
    const float* wptr = Wm + (size_t)brow * kHID + n0 + bcol;
    float acc[4][4] = {};
    for (int k0 = 0; k0 < kVIS; k0 += BK) {
        const float4 a4 = *(const float4*)(vptr + k0);
        const float4 b4 = *(const float4*)(wptr + (size_t)k0 * kHID);
        __syncthreads();
        As[acol + 0][arow] = a4.x; As[acol + 1][arow] = a4.y;
        As[acol + 2][arow] = a4.z; As[acol + 3][arow] = a4.w;
        *(float4*)&Bs[brow][bcol] = b4;
        __syncthreads();
#pragma unroll
        for (int k = 0; k < BK; ++k) {
            const float4 av = *(const float4*)&As[k][ty << 2];
            const float4 bv = *(const float4*)&Bs[k][tx << 2];
            const float a[4] = {av.x, av.y, av.z, av.w};
            const float b[4] = {bv.x, bv.y, bv.z, bv.w};
#pragma unroll
            for (int i = 0; i < 4; ++i)
#pragma unroll
                for (int j = 0; j < 4; ++j) acc[i][j] += a[i] * b[j];
        }
    }
#pragma unroll
    for (int i = 0; i < 4; ++i) {
        const int row = m0 + (ty << 2) + i;
        const int col = n0 + (tx << 2);
        const float4 cv = *(const float4*)(cvec + col);
        float4 o;
        o.x = acc[i][0] + cv.x; o.y = acc[i][1] + cv.y;
        o.z = acc[i][2] + cv.z; o.w = acc[i][3] + cv.w;
        *(float4*)(pre + (size_t)row * kHID + col) = o;
    }
}

__device__ __forceinline__ float softplus_f(float x) {
    return fmaxf(x, 0.f) + __logf(1.f + __expf(-fabsf(x)));
}

__global__ __launch_bounds__(256) void classify(const float* __restrict__ pre,
                                                const float* __restrict__ U,
                                                const float* __restrict__ dvec,
                                                float* __restrict__ out) {
    __shared__ float preS[4][kHID];
    __shared__ float Fs[4][kCLS];
    const int tid = threadIdx.x;
    const int lane = tid & 63, wave = tid >> 6;
    const int b0 = blockIdx.x * 4;
    const float4* src = (const float4*)(pre + (size_t)b0 * kHID);
    float4* dst = (float4*)preS;
    for (int i = tid; i < kHID; i += 256) dst[i] = src[i];
    __syncthreads();
    for (int yi = 0; yi < 16; ++yi) {
        const int y = (wave << 4) + yi;
        const float* Uy = U + (size_t)y * kHID;
        float a0 = 0.f, a1 = 0.f, a2 = 0.f, a3 = 0.f;
#pragma unroll
        for (int it = 0; it < kHID / 64; ++it) {
            const int j = lane + (it << 6);
            const float u = Uy[j];
            a0 += softplus_f(preS[0][j] + u);
            a1 += softplus_f(preS[1][j] + u);
            a2 += softplus_f(preS[2][j] + u);
            a3 += softplus_f(preS[3][j] + u);
        }
        double d0 = a0, d1 = a1, d2 = a2, d3 = a3;
#pragma unroll
        for (int off = 32; off; off >>= 1) {
            d0 += __shfl_xor(d0, off); d1 += __shfl_xor(d1, off);
            d2 += __shfl_xor(d2, off); d3 += __shfl_xor(d3, off);
        }
        if (lane == 0) {
            const float dy = dvec[y];
            Fs[0][y] = (float)d0 + dy; Fs[1][y] = (float)d1 + dy;
            Fs[2][y] = (float)d2 + dy; Fs[3][y] = (float)d3 + dy;
        }
    }
    __syncthreads();
    const float F = Fs[wave][lane];
    float m = F; int mi = lane;
#pragma unroll
    for (int off = 32; off; off >>= 1) {
        const float om = __shfl_xor(m, off);
        const int oi = __shfl_xor(mi, off);
        if (om > m || (om == m && oi < mi)) { m = om; mi = oi; }
    }
    const float e = __expf(F - m);
    float s = e;
#pragma unroll
    for (int off = 32; off; off >>= 1) s += __shfl_xor(s, off);
    const int row = b0 + wave;
    out[(size_t)row * kCLS + lane] = e / s;
    out[(size_t)kB * kCLS + (size_t)row * kCLS + lane] = (lane == mi) ? 1.0f : 0.0f;
}

extern "C" void kernel_launch(void* const* d_in, const int* in_sizes, int n_in,
                              void* d_out, int out_size, void* d_ws, size_t ws_size,
                              hipStream_t stream) {
    const float* v = (const float*)d_in[0];
    const float* W = (const float*)d_in[1];
    const float* c = (const float*)d_in[2];
    const float* d = (const float*)d_in[3];
    const float* U = (const float*)d_in[4];
    float* out = (float*)d_out;
    char* ws = (char*)d_ws;

    // ws layout: vh 8MB | vl 8MB | Wt_h 4MB | Wt_l 4MB | Ut 256KB | Fpart 8MB
    const size_t need = 33816576;
    if (ws_size >= need) {
        unsigned short* vh  = (unsigned short*)(ws);
        unsigned short* vl  = (unsigned short*)(ws + 8388608);
        unsigned short* wth = (unsigned short*)(ws + 16777216);
        unsigned short* wtl = (unsigned short*)(ws + 20971520);
        float* Ut    = (float*)(ws + 25165824);
        float* Fpart = (float*)(ws + 25427968);
        prep_all<<<6400, 256, 0, stream>>>(v, W, U, vh, vl, wth, wtl, Ut);
        gemm_fused<<<dim3(kHID / 64, kB / 64), 256, 0, stream>>>(vh, vl, wth, wtl, c, Ut, Fpart);
        softmax_final<<<kB / 4, 256, 0, stream>>>(Fpart, d, out);
    } else {
        float* pre = (float*)ws;
        gemm_vw<<<dim3(kHID / BN, kB / BM), 256, 0, stream>>>(v, W, c, pre);
        classify<<<kB / 4, 256, 0, stream>>>(pre, U, d, out);
    }
}

// Round 4
// 135.993 us; speedup vs baseline: 1.9858x; 1.0597x over previous
//
#include <hip/hip_runtime.h>

// Problem sizes (fixed by the reference)
constexpr int kB    = 2048;  // batch
constexpr int kVIS  = 2048;  // visible units (GEMM K)
constexpr int kHID  = 1024;  // hidden units (GEMM N)
constexpr int kCLS  = 64;    // classes
constexpr float kLog2e = 1.4426950408889634f;

typedef __attribute__((ext_vector_type(8))) short bf16x8;
typedef __attribute__((ext_vector_type(4))) float f32x4;

typedef __attribute__((address_space(3))) unsigned       as3_u32;
typedef __attribute__((address_space(1))) const unsigned as1_u32;

__device__ __forceinline__ void g2lds16(const void* g, void* l) {
    // async global->LDS DMA, 16 B per lane; LDS dest is wave-base + lane*16
    __builtin_amdgcn_global_load_lds((as1_u32*)g, (as3_u32*)l, 16, 0, 0);
}

__device__ __forceinline__ unsigned short f2bf(float x) {
    unsigned u = __float_as_uint(x);
    u += 0x7fffu + ((u >> 16) & 1u);
    return (unsigned short)(u >> 16);
}
__device__ __forceinline__ float bf2f(unsigned short h) {
    return __uint_as_float(((unsigned)h) << 16);
}

// ---------------- Prep (merged): split v, split+transpose W, scale+transpose U ----------
// blocks [0,4096): split_v ; [4096,6144): split_w_t ; [6144,6400): scale_u_t
__global__ __launch_bounds__(256) void prep_all(const float* __restrict__ v,
                                                const float* __restrict__ W,
                                                const float* __restrict__ U,
                                                unsigned short* __restrict__ vh,
                                                unsigned short* __restrict__ vl,
                                                unsigned short* __restrict__ wth,
                                                unsigned short* __restrict__ wtl,
                                                float* __restrict__ Ut) {
    __shared__ float T[32][33];
    const int bx = blockIdx.x;
    if (bx < 4096) {
        const int i = (bx * 256 + threadIdx.x) * 4;
        const float4 xv = *(const float4*)(v + i);
        ushort4 h, l;
        h.x = f2bf(xv.x); l.x = f2bf(xv.x - bf2f(h.x));
        h.y = f2bf(xv.y); l.y = f2bf(xv.y - bf2f(h.y));
        h.z = f2bf(xv.z); l.z = f2bf(xv.z - bf2f(h.z));
        h.w = f2bf(xv.w); l.w = f2bf(xv.w - bf2f(h.w));
        *(ushort4*)(vh + i) = h;
        *(ushort4*)(vl + i) = l;
    } else if (bx < 6144) {
        const int b = bx - 4096;
        const int n0 = (b & 31) * 32, k0 = (b >> 5) * 32;
        const int c = threadIdx.x & 31, r0 = threadIdx.x >> 5;
#pragma unroll
        for (int p = 0; p < 4; ++p) {
            const int r = r0 + p * 8;
            T[r][c] = W[(size_t)(k0 + r) * kHID + n0 + c];
        }
        __syncthreads();
#pragma unroll
        for (int p = 0; p < 4; ++p) {
            const int rr = r0 + p * 8;          // n offset
            const float x = T[c][rr];           // = W[k0+c][n0+rr]
            const unsigned short h = f2bf(x);
            const unsigned short l = f2bf(x - bf2f(h));
            const size_t o = (size_t)(n0 + rr) * kVIS + k0 + c;
            wth[o] = h;
            wtl[o] = l;
        }
    } else {
        const int id = (bx - 6144) * 256 + threadIdx.x;  // 0..65535
        const int j = id >> 6, y = id & 63;
        Ut[id] = U[(size_t)y * kHID + j] * kLog2e;
    }
}

// ---------------- Fused kernel: split-bf16 MFMA GEMM + softplus partial-F epilogue ------
// 64x64 tile, 4 waves (32x32 quadrants, 2x2 of mfma_f32_16x16x32_bf16, 3 products).
// Staging: global_load_lds width=16 with XOR-swizzled k-octets (LDK=64, no pad:
// physical octet p at row r holds global octet p^(r&7); frag reads are 2-way = free).
// Epilogue: acc -> ps[64][68] LDS (2-way writes), inverted loop with relu[16]/prod[16]
// in VGPRs, Ut read direct from global (coalesced, L2-hot).
__global__ __launch_bounds__(256) void gemm_fused(const unsigned short* __restrict__ vh,
                                                  const unsigned short* __restrict__ vl,
                                                  const unsigned short* __restrict__ wth,
                                                  const unsigned short* __restrict__ wtl,
                                                  const float* __restrict__ cvec,
                                                  const float* __restrict__ Ut,
                                                  float* __restrict__ Fpart) {
    __shared__ __align__(16) union SMem {
        unsigned short stage[4][64 * 64];   // Ah, Al, Bh, Bl  (32768 B)
        float ps[64][68];                   // 17408 B, overlays stage
    } smem;
    unsigned short* Ah = smem.stage[0];
    unsigned short* Al = smem.stage[1];
    unsigned short* Bh = smem.stage[2];
    unsigned short* Bl = smem.stage[3];

    const int tid = threadIdx.x;
    const int lane = tid & 63, wave = tid >> 6;
    const int m0 = blockIdx.y * 64, n0 = blockIdx.x * 64;
    const int wm = (wave >> 1) * 32, wn = (wave & 1) * 32;

    // staging: thread covers rows r0 and r0+32; k-octet XOR-swizzled on global side
    const int r0 = tid >> 3, r1 = r0 + 32;
    const int oc = (((tid & 7) ^ ((tid >> 3) & 7)) << 3);   // global k-octet offset (elems)
    const size_t ga0 = (size_t)(m0 + r0) * kVIS + oc;
    const size_t ga1 = (size_t)(m0 + r1) * kVIS + oc;
    const size_t gb0 = (size_t)(n0 + r0) * kVIS + oc;
    const size_t gb1 = (size_t)(n0 + r1) * kVIS + oc;
    const int l0 = (r0 << 6) + ((tid & 7) << 3);            // physical LDS slot (elems)
    const int l1 = (r1 << 6) + ((tid & 7) << 3);

    // fragment addressing: A[m=lane&15][k], row-major LDK=64, swizzled octet
    const int fm = lane & 15, fq = lane >> 4;
    const int rx = fm & 7;                                  // row xor key (rows +16/+32 same &7)
    const int a0r = (wm + fm) << 6,  a1r = (wm + 16 + fm) << 6;
    const int b0r = (wn + fm) << 6,  b1r = (wn + 16 + fm) << 6;

    f32x4 acc[2][2] = {};

    for (int k0 = 0; k0 < kVIS; k0 += 64) {
        __syncthreads();  // prior compute done reading LDS
        g2lds16(vh + ga0 + k0, Ah + l0);
        g2lds16(vh + ga1 + k0, Ah + l1);
        g2lds16(vl + ga0 + k0, Al + l0);
        g2lds16(vl + ga1 + k0, Al + l1);
        g2lds16(wth + gb0 + k0, Bh + l0);
        g2lds16(wth + gb1 + k0, Bh + l1);
        g2lds16(wtl + gb0 + k0, Bl + l0);
        g2lds16(wtl + gb1 + k0, Bl + l1);
        __syncthreads();  // drains vmcnt -> staged data visible
#pragma unroll
        for (int kk = 0; kk < 64; kk += 32) {
            const int p = (((kk >> 3) + fq) ^ rx) << 3;     // swizzled octet (elems)
            const bf16x8 ah0 = *(const bf16x8*)(Ah + a0r + p);
            const bf16x8 ah1 = *(const bf16x8*)(Ah + a1r + p);
            const bf16x8 al0 = *(const bf16x8*)(Al + a0r + p);
            const bf16x8 al1 = *(const bf16x8*)(Al + a1r + p);
            const bf16x8 bh0 = *(const bf16x8*)(Bh + b0r + p);
            const bf16x8 bh1 = *(const bf16x8*)(Bh + b1r + p);
            const bf16x8 bl0 = *(const bf16x8*)(Bl + b0r + p);
            const bf16x8 bl1 = *(const bf16x8*)(Bl + b1r + p);
            acc[0][0] = __builtin_amdgcn_mfma_f32_16x16x32_bf16(ah0, bh0, acc[0][0], 0, 0, 0);
            acc[0][0] = __builtin_amdgcn_mfma_f32_16x16x32_bf16(ah0, bl0, acc[0][0], 0, 0, 0);
            acc[0][0] = __builtin_amdgcn_mfma_f32_16x16x32_bf16(al0, bh0, acc[0][0], 0, 0, 0);
            acc[0][1] = __builtin_amdgcn_mfma_f32_16x16x32_bf16(ah0, bh1, acc[0][1], 0, 0, 0);
            acc[0][1] = __builtin_amdgcn_mfma_f32_16x16x32_bf16(ah0, bl1, acc[0][1], 0, 0, 0);
            acc[0][1] = __builtin_amdgcn_mfma_f32_16x16x32_bf16(al0, bh1, acc[0][1], 0, 0, 0);
            acc[1][0] = __builtin_amdgcn_mfma_f32_16x16x32_bf16(ah1, bh0, acc[1][0], 0, 0, 0);
            acc[1][0] = __builtin_amdgcn_mfma_f32_16x16x32_bf16(ah1, bl0, acc[1][0], 0, 0, 0);
            acc[1][0] = __builtin_amdgcn_mfma_f32_16x16x32_bf16(al1, bh0, acc[1][0], 0, 0, 0);
            acc[1][1] = __builtin_amdgcn_mfma_f32_16x16x32_bf16(ah1, bh1, acc[1][1], 0, 0, 0);
            acc[1][1] = __builtin_amdgcn_mfma_f32_16x16x32_bf16(ah1, bl1, acc[1][1], 0, 0, 0);
            acc[1][1] = __builtin_amdgcn_mfma_f32_16x16x32_bf16(al1, bh1, acc[1][1], 0, 0, 0);
        }
    }

    // ---- epilogue phase 1: pre-tile -> ps (log2 domain, +c); 2-way writes (stride 68)
    __syncthreads();  // all waves done reading stage LDS (union overlay)
#pragma unroll
    for (int j = 0; j < 2; ++j) {
        const int col = wn + j * 16 + fm;              // local hid col 0..63
        const float cv = cvec[n0 + col];
#pragma unroll
        for (int i = 0; i < 2; ++i) {
            const int rbase = wm + i * 16 + fq * 4;    // local row
#pragma unroll
            for (int r = 0; r < 4; ++r)
                smem.ps[rbase + r][col] = (acc[i][j][r] + cv) * kLog2e;
        }
    }
    __syncthreads();

    // ---- epilogue phase 2: inverted loop; wave owns rows [wave*16,+16), lane = class
    const float* UtN = Ut + (size_t)n0 * kCLS;
    float relu[16], prod[16];
#pragma unroll
    for (int rr = 0; rr < 16; ++rr) { relu[rr] = 0.f; prod[rr] = 1.f; }

    for (int jc = 0; jc < 64; jc += 8) {
        float u[8];
#pragma unroll
        for (int q = 0; q < 8; ++q) u[q] = UtN[(jc + q) * kCLS + lane];  // global, L2-hot
#pragma unroll
        for (int rr = 0; rr < 16; ++rr) {
            const float4 p0 = *(const float4*)&smem.ps[wave * 16 + rr][jc];      // broadcast
            const float4 p1 = *(const float4*)&smem.ps[wave * 16 + rr][jc + 4];  // broadcast
            const float pv[8] = {p0.x, p0.y, p0.z, p0.w, p1.x, p1.y, p1.z, p1.w};
#pragma unroll
            for (int q = 0; q < 8; ++q) {
                const float t = pv[q] + u[q];
                const float e = __builtin_amdgcn_exp2f(-fabsf(t));  // 2^-|t|
                prod[rr] = __builtin_fmaf(prod[rr], e, prod[rr]);   // prod *= (1+e), max 2^64
                relu[rr] += fmaxf(t, 0.f);
            }
        }
    }
#pragma unroll
    for (int rr = 0; rr < 16; ++rr) {
        const float contrib = relu[rr] + __builtin_amdgcn_logf(prod[rr]);  // log2 domain
        Fpart[((size_t)blockIdx.x * kB + m0 + wave * 16 + rr) * kCLS + lane] = contrib;
    }
}

// ---------------- Final: sum 16 partials (double), softmax, argmax, one-hot ------------
__global__ __launch_bounds__(256) void softmax_final(const float* __restrict__ Fpart,
                                                     const float* __restrict__ dvec,
                                                     float* __restrict__ out) {
    const int tid = threadIdx.x;
    const int lane = tid & 63, wave = tid >> 6;
    const int row = blockIdx.x * 4 + wave;
    double s = 0.0;
#pragma unroll
    for (int k = 0; k < kHID / 64; ++k)
        s += (double)Fpart[((size_t)k * kB + row) * kCLS + lane];
    const float G = (float)s + dvec[lane] * kLog2e;  // log2-domain logit

    float m = G;
    int mi = lane;
#pragma unroll
    for (int off = 32; off; off >>= 1) {
        const float om = __shfl_xor(m, off);
        const int   oi = __shfl_xor(mi, off);
        if (om > m || (om == m && oi < mi)) { m = om; mi = oi; }  // first-index tie-break
    }
    const float e2 = __builtin_amdgcn_exp2f(G - m);
    float ssum = e2;
#pragma unroll
    for (int off = 32; off; off >>= 1) ssum += __shfl_xor(ssum, off);
    out[(size_t)row * kCLS + lane] = e2 / ssum;
    out[(size_t)kB * kCLS + (size_t)row * kCLS + lane] = (lane == mi) ? 1.0f : 0.0f;
}

// ================= Fallback (round-1, known-passing) if ws is too small =================
constexpr int BM = 64, BN = 64, BK = 16;

__global__ __launch_bounds__(256) void gemm_vw(const float* __restrict__ V,
                                               const float* __restrict__ Wm,
                                               const float* __restrict__ cvec,
                                               float* __restrict__ pre) {
    __shared__ float As[BK][BM + 4];
    __shared__ float Bs[BK][BN + 4];
    const int tid = threadIdx.x;
    const int tx = tid & 15, ty = tid >> 4;
    const int m0 = blockIdx.y * BM, n0 = blockIdx.x * BN;
    const int arow = tid >> 2, acol = (tid & 3) << 2;
    const int brow = tid >> 4, bcol = (tid & 15) << 2;
    const float* vptr = V + (size_t)(m0 + arow) * kVIS + acol;
    const float* wptr = Wm + (size_t)brow * kHID + n0 + bcol;
    float acc[4][4] = {};
    for (int k0 = 0; k0 < kVIS; k0 += BK) {
        const float4 a4 = *(const float4*)(vptr + k0);
        const float4 b4 = *(const float4*)(wptr + (size_t)k0 * kHID);
        __syncthreads();
        As[acol + 0][arow] = a4.x; As[acol + 1][arow] = a4.y;
        As[acol + 2][arow] = a4.z; As[acol + 3][arow] = a4.w;
        *(float4*)&Bs[brow][bcol] = b4;
        __syncthreads();
#pragma unroll
        for (int k = 0; k < BK; ++k) {
            const float4 av = *(const float4*)&As[k][ty << 2];
            const float4 bv = *(const float4*)&Bs[k][tx << 2];
            const float a[4] = {av.x, av.y, av.z, av.w};
            const float b[4] = {bv.x, bv.y, bv.z, bv.w};
#pragma unroll
            for (int i = 0; i < 4; ++i)
#pragma unroll
                for (int j = 0; j < 4; ++j) acc[i][j] += a[i] * b[j];
        }
    }
#pragma unroll
    for (int i = 0; i < 4; ++i) {
        const int row = m0 + (ty << 2) + i;
        const int col = n0 + (tx << 2);
        const float4 cv = *(const float4*)(cvec + col);
        float4 o;
        o.x = acc[i][0] + cv.x; o.y = acc[i][1] + cv.y;
        o.z = acc[i][2] + cv.z; o.w = acc[i][3] + cv.w;
        *(float4*)(pre + (size_t)row * kHID + col) = o;
    }
}

__device__ __forceinline__ float softplus_f(float x) {
    return fmaxf(x, 0.f) + __logf(1.f + __expf(-fabsf(x)));
}

__global__ __launch_bounds__(256) void classify(const float* __restrict__ pre,
                                                const float* __restrict__ U,
                                                const float* __restrict__ dvec,
                                                float* __restrict__ out) {
    __shared__ float preS[4][kHID];
    __shared__ float Fs[4][kCLS];
    const int tid = threadIdx.x;
    const int lane = tid & 63, wave = tid >> 6;
    const int b0 = blockIdx.x * 4;
    const float4* src = (const float4*)(pre + (size_t)b0 * kHID);
    float4* dst = (float4*)preS;
    for (int i = tid; i < kHID; i += 256) dst[i] = src[i];
    __syncthreads();
    for (int yi = 0; yi < 16; ++yi) {
        const int y = (wave << 4) + yi;
        const float* Uy = U + (size_t)y * kHID;
        float a0 = 0.f, a1 = 0.f, a2 = 0.f, a3 = 0.f;
#pragma unroll
        for (int it = 0; it < kHID / 64; ++it) {
            const int j = lane + (it << 6);
            const float u = Uy[j];
            a0 += softplus_f(preS[0][j] + u);
            a1 += softplus_f(preS[1][j] + u);
            a2 += softplus_f(preS[2][j] + u);
            a3 += softplus_f(preS[3][j] + u);
        }
        double d0 = a0, d1 = a1, d2 = a2, d3 = a3;
#pragma unroll
        for (int off = 32; off; off >>= 1) {
            d0 += __shfl_xor(d0, off); d1 += __shfl_xor(d1, off);
            d2 += __shfl_xor(d2, off); d3 += __shfl_xor(d3, off);
        }
        if (lane == 0) {
            const float dy = dvec[y];
            Fs[0][y] = (float)d0 + dy; Fs[1][y] = (float)d1 + dy;
            Fs[2][y] = (float)d2 + dy; Fs[3][y] = (float)d3 + dy;
        }
    }
    __syncthreads();
    const float F = Fs[wave][lane];
    float m = F; int mi = lane;
#pragma unroll
    for (int off = 32; off; off >>= 1) {
        const float om = __shfl_xor(m, off);
        const int oi = __shfl_xor(mi, off);
        if (om > m || (om == m && oi < mi)) { m = om; mi = oi; }
    }
    const float e = __expf(F - m);
    float s = e;
#pragma unroll
    for (int off = 32; off; off >>= 1) s += __shfl_xor(s, off);
    const int row = b0 + wave;
    out[(size_t)row * kCLS + lane] = e / s;
    out[(size_t)kB * kCLS + (size_t)row * kCLS + lane] = (lane == mi) ? 1.0f : 0.0f;
}

extern "C" void kernel_launch(void* const* d_in, const int* in_sizes, int n_in,
                              void* d_out, int out_size, void* d_ws, size_t ws_size,
                              hipStream_t stream) {
    const float* v = (const float*)d_in[0];
    const float* W = (const float*)d_in[1];
    const float* c = (const float*)d_in[2];
    const float* d = (const float*)d_in[3];
    const float* U = (const float*)d_in[4];
    float* out = (float*)d_out;
    char* ws = (char*)d_ws;

    // ws layout: vh 8MB | vl 8MB | Wt_h 4MB | Wt_l 4MB | Ut 256KB | Fpart 8MB
    const size_t need = 33816576;
    if (ws_size >= need) {
        unsigned short* vh  = (unsigned short*)(ws);
        unsigned short* vl  = (unsigned short*)(ws + 8388608);
        unsigned short* wth = (unsigned short*)(ws + 16777216);
        unsigned short* wtl = (unsigned short*)(ws + 20971520);
        float* Ut    = (float*)(ws + 25165824);
        float* Fpart = (float*)(ws + 25427968);
        prep_all<<<6400, 256, 0, stream>>>(v, W, U, vh, vl, wth, wtl, Ut);
        gemm_fused<<<dim3(kHID / 64, kB / 64), 256, 0, stream>>>(vh, vl, wth, wtl, c, Ut, Fpart);
        softmax_final<<<kB / 4, 256, 0, stream>>>(Fpart, d, out);
    } else {
        float* pre = (float*)ws;
        gemm_vw<<<dim3(kHID / BN, kB / BM), 256, 0, stream>>>(v, W, c, pre);
        classify<<<kB / 4, 256, 0, stream>>>(pre, U, d, out);
    }
}